// Round 2
// 133.377 us; speedup vs baseline: 1.0672x; 1.0672x over previous
//
#include <hip/hip_runtime.h>
#include <cstdint>

#define NAG 25
#define NS 32
#define EHH 3200      // EHH_HID
#define KDIM 800      // N_AGENT*N_S
#define BATCH 2048
#define NEDGE 300
#define NPAD 384      // 300 padded to 3x128
#define KSPLIT 5

typedef _Float16 half8 __attribute__((ext_vector_type(8)));
typedef float f32x4 __attribute__((ext_vector_type(4)));

__device__ __forceinline__ float leaky(float x) { return x >= 0.f ? x : 0.01f * x; }

// ================= K1: all order-independent prep =================
// blocks [0,25): per-agent batch stats -> mean/rstd (no atomics, no init pass)
// blocks [25,2525): ehh_w transpose 800x3200 f32 -> 3200x800 fp16
// blocks [2525,2970): W2dT build; each block replays edge scatter in LDS (no dep)
__global__ __launch_bounds__(256)
void prep1_kernel(const float* __restrict__ states, const float* __restrict__ ehh_w,
                  const int* __restrict__ adj, const float* __restrict__ anova,
                  const float* __restrict__ w1,
                  float* __restrict__ mean, float* __restrict__ rstd,
                  _Float16* __restrict__ wt, _Float16* __restrict__ w2dt) {
    __shared__ float redS[32][32];
    __shared__ float redQ[32][32];
    __shared__ float tile[32][33];
    __shared__ int win[EHH];
    const int bi = blockIdx.x;
    const int tid = threadIdx.x;

    if (bi < 25) {
        // ---- stats for agent bi: 2048x32, each thread 64 float4 loads ----
        const int a = bi;
        const int s4 = (tid & 7) << 2;     // column group (0,4,...,28)
        const int r0 = tid >> 3;           // row group 0..31
        const float* base = states + ((size_t)a * BATCH + r0) * NS + s4;
        f32x4 sum = {0.f, 0.f, 0.f, 0.f};
        f32x4 sq  = {0.f, 0.f, 0.f, 0.f};
#pragma unroll 8
        for (int it = 0; it < 64; ++it) {
            f32x4 v = *(const f32x4*)(base + (size_t)it * 32 * NS);
            sum += v;
            sq  += v * v;
        }
        *(f32x4*)&redS[r0][s4] = sum;
        *(f32x4*)&redQ[r0][s4] = sq;
        __syncthreads();
        if (tid < 32) {
            float s = 0.f, q = 0.f;
#pragma unroll
            for (int r = 0; r < 32; ++r) { s += redS[r][tid]; q += redQ[r][tid]; }
            float m = s * (1.f / BATCH);
            float var = q * (1.f / BATCH) - m * m;
            mean[a * 32 + tid] = m;
            rstd[a * 32 + tid] = rsqrtf(var + 1e-5f);
        }
    } else if (bi < 2525) {
        // ---- transpose ehh_w (f32, 800xEHH) -> wt (fp16, EHHx800) ----
        const int bb = bi - 25;
        const int n0 = (bb % 100) * 32, k0 = (bb / 100) * 32;
        const int x = tid & 31, y = tid >> 5;
        for (int i = y; i < 32; i += 8)
            tile[i][x] = ehh_w[(size_t)(k0 + i) * EHH + n0 + x];
        __syncthreads();
        for (int i = y; i < 32; i += 8)
            wt[(size_t)(n0 + i) * KDIM + k0 + x] = (_Float16)tile[x][i];
    } else {
        const int bb = bi - 2525;
        if (bb < 313) {
            // ---- per-block LDS edge scatter replay (600 entries, strided) ----
            for (int h = tid; h < EHH; h += 256) win[h] = -1;
            __syncthreads();
            for (int e = tid; e < 2 * NEDGE; e += 256) {
                int pass = e >= NEDGE;
                int ee = pass ? e - NEDGE : e;
                int dest = adj[ee * 4 + (pass ? 3 : 1)];
                atomicMax(&win[dest], e);   // prio = entry index; pass2 > pass1
            }
            __syncthreads();
            // ---- W2dT[a*12+k][h] = att(h,a) * w1[a,h,k] ----
            int t = bb * 256 + tid;   // t = a*3200 + h
            if (t < NAG * EHH) {
                int a = t / EHH;
                int h = t - a * EHH;
                float att = anova[(size_t)h * NAG + a];
                int w = win[h];
                if (w >= 0) {
                    int ee = w >= NEDGE ? w - NEDGE : w;
                    att += anova[(size_t)(EHH + adj[ee * 4]) * NAG + a];
                }
                const float* wp = w1 + ((size_t)a * EHH + h) * 12;
#pragma unroll
                for (int kk = 0; kk < 12; ++kk)
                    w2dt[(size_t)(a * 12 + kk) * EHH + h] = (_Float16)(att * wp[kk]);
            }
        } else {
            // pad rows 300..383 -> zero, 16B per thread
            int p = (bb - 313) * 256 + tid;
            if (p < (NPAD - 300) * EHH / 8) {
                half8 z = {0, 0, 0, 0, 0, 0, 0, 0};
                ((half8*)(w2dt + (size_t)300 * EHH))[p] = z;
            }
        }
    }
}

// ================= K2: normalize -> A fp16, 8 elems/thread =================
__global__ __launch_bounds__(256)
void norm_kernel(const float* __restrict__ states, const float* __restrict__ mean,
                 const float* __restrict__ rstd, _Float16* __restrict__ A) {
    int u = blockIdx.x * 256 + threadIdx.x;   // [0, 204800)
    int b = u / 100;
    int fo = (u - b * 100) * 8;               // feature offset, multiple of 8
    int a = fo >> 5, s = fo & 31;
    const float* sp = states + ((size_t)a * BATCH + b) * NS + s;
    f32x4 v0 = *(const f32x4*)sp;
    f32x4 v1 = *(const f32x4*)(sp + 4);
    f32x4 m0 = *(const f32x4*)(mean + fo);
    f32x4 m1 = *(const f32x4*)(mean + fo + 4);
    f32x4 r0 = *(const f32x4*)(rstd + fo);
    f32x4 r1 = *(const f32x4*)(rstd + fo + 4);
    half8 out;
#pragma unroll
    for (int i = 0; i < 4; ++i) out[i] = (_Float16)((v0[i] - m0[i]) * r0[i]);
#pragma unroll
    for (int i = 0; i < 4; ++i) out[4 + i] = (_Float16)((v1[i] - m1[i]) * r1[i]);
    *(half8*)(A + (size_t)b * KDIM + fo) = out;
}

// ---------------- 128x128 MFMA GEMM, C = A(MxK) * B^T(NxK), fp16 k-contiguous ----------------
// Double-buffered LDS: one barrier per K-iteration; loads for tile k+1 fly during MFMA of tile k.
__device__ __forceinline__ void async16(const void* g, void* l) {
    __builtin_amdgcn_global_load_lds(
        (const __attribute__((address_space(1))) void*)(uintptr_t)g,
        (__attribute__((address_space(3))) void*)(unsigned)(uintptr_t)l, 16, 0, 0);
}

template <bool LEAKY_F16_OUT>
__global__ __launch_bounds__(256)
void gemm_bt(const _Float16* __restrict__ A, const _Float16* __restrict__ B,
             _Float16* __restrict__ Ch, float* __restrict__ Cf,
             int Ktot, int ldc, int kPerSplit, int slabStride) {
    __shared__ __attribute__((aligned(16))) _Float16 As[2][128 * 32];
    __shared__ __attribute__((aligned(16))) _Float16 Bs[2][128 * 32];
    const int tid = threadIdx.x;
    const int lane = tid & 63;
    const int wave = tid >> 6;            // 4 waves, 2x2
    const int wm = (wave >> 1) << 6;
    const int wn = (wave & 1) << 6;
    const int m0 = blockIdx.x << 7;
    const int n0 = blockIdx.y << 7;
    const int k0 = blockIdx.z * kPerSplit;
    const int nk = kPerSplit >> 5;

    // staging: each wave covers 16 rows per issue (64 lanes * 16B = 16 rows * 64B)
    const int srow = lane >> 2;
    const int scol = (lane & 3) << 3;
    const _Float16* gA0 = A + (size_t)(m0 + wave * 16 + srow) * Ktot + k0 + scol;
    const _Float16* gA1 = gA0 + (size_t)64 * Ktot;
    const _Float16* gB0 = B + (size_t)(n0 + wave * 16 + srow) * Ktot + k0 + scol;
    const _Float16* gB1 = gB0 + (size_t)64 * Ktot;
    const int lofs = wave * 512;

    f32x4 acc[4][4];
    const f32x4 zero = {0.f, 0.f, 0.f, 0.f};
#pragma unroll
    for (int i = 0; i < 4; ++i)
#pragma unroll
        for (int j = 0; j < 4; ++j) acc[i][j] = zero;

    const int fr = lane & 15;             // m (A) / n (B) within 16-tile
    const int q8 = (lane >> 4) << 3;      // k offset of this lane's 8 elements

    // prologue: stage tile 0 into buffer 0
    async16(gA0, As[0] + lofs);
    async16(gA1, As[0] + 2048 + lofs);
    async16(gB0, Bs[0] + lofs);
    async16(gB1, Bs[0] + 2048 + lofs);

    for (int kt = 0; kt < nk; ++kt) {
        const int cur = kt & 1;
        __syncthreads();   // drains vmcnt(0): buf[cur] staged; all readers of buf[cur^1] done
        if (kt + 1 < nk) {
            const int ko = (kt + 1) << 5;
            const int nxt = cur ^ 1;
            async16(gA0 + ko, As[nxt] + lofs);
            async16(gA1 + ko, As[nxt] + 2048 + lofs);
            async16(gB0 + ko, Bs[nxt] + lofs);
            async16(gB1 + ko, Bs[nxt] + 2048 + lofs);
        }
        half8 av[4], bv[4];
#pragma unroll
        for (int i = 0; i < 4; ++i)
            av[i] = *(const half8*)(As[cur] + (wm + i * 16 + fr) * 32 + q8);
#pragma unroll
        for (int j = 0; j < 4; ++j)
            bv[j] = *(const half8*)(Bs[cur] + (wn + j * 16 + fr) * 32 + q8);
#pragma unroll
        for (int i = 0; i < 4; ++i)
#pragma unroll
            for (int j = 0; j < 4; ++j)
                acc[i][j] = __builtin_amdgcn_mfma_f32_16x16x32_f16(av[i], bv[j], acc[i][j], 0, 0, 0);
    }

    // C/D layout: col = lane&15, row = (lane>>4)*4 + reg   [m89-verified]
    const int r0 = (lane >> 4) << 2;
    if (LEAKY_F16_OUT) {
#pragma unroll
        for (int i = 0; i < 4; ++i)
#pragma unroll
            for (int j = 0; j < 4; ++j)
#pragma unroll
                for (int r = 0; r < 4; ++r) {
                    int row = m0 + wm + i * 16 + r0 + r;
                    int col = n0 + wn + j * 16 + fr;
                    Ch[(size_t)row * ldc + col] = (_Float16)leaky(acc[i][j][r]);
                }
    } else {
        float* C = Cf + (size_t)blockIdx.z * slabStride;
#pragma unroll
        for (int i = 0; i < 4; ++i)
#pragma unroll
            for (int j = 0; j < 4; ++j)
#pragma unroll
                for (int r = 0; r < 4; ++r) {
                    int row = m0 + wm + i * 16 + r0 + r;
                    int col = n0 + wn + j * 16 + fr;
                    C[(size_t)row * ldc + col] = acc[i][j][r];
                }
    }
}

// ---------------- tail: reduce split-K, bias+leaky, 12x12, 12x4, action gather ----------------
__global__ void tail_kernel(const float* __restrict__ Hp, const float* __restrict__ b1,
                            const float* __restrict__ w2, const float* __restrict__ b2,
                            const float* __restrict__ w3, const float* __restrict__ b3,
                            const int* __restrict__ act, float* __restrict__ out) {
    int t = blockIdx.x * 256 + threadIdx.x;   // t = a*2048 + b
    int b = t & (BATCH - 1);
    int a = t >> 11;
    const float* hp = Hp + (size_t)b * NPAD + a * 12;
    float h1[12];
#pragma unroll
    for (int k = 0; k < 12; ++k) {
        float s = b1[a * 12 + k];
#pragma unroll
        for (int ks = 0; ks < KSPLIT; ++ks) s += hp[(size_t)ks * BATCH * NPAD + k];
        h1[k] = leaky(s);
    }
    float h2[12];
#pragma unroll
    for (int j = 0; j < 12; ++j) {
        float s = b2[a * 12 + j];
#pragma unroll
        for (int k = 0; k < 12; ++k) s += h1[k] * w2[(a * 12 + k) * 12 + j];
        h2[j] = leaky(s);
    }
    int c = act[t];
    float q = b3[a * 4 + c];
#pragma unroll
    for (int j = 0; j < 12; ++j) q += h2[j] * w3[(a * 12 + j) * 4 + c];
    out[t] = q;
}

extern "C" void kernel_launch(void* const* d_in, const int* in_sizes, int n_in,
                              void* d_out, int out_size, void* d_ws, size_t ws_size,
                              hipStream_t stream) {
    (void)in_sizes; (void)n_in; (void)out_size; (void)ws_size;
    const float* states = (const float*)d_in[0];
    const float* ehh_w  = (const float*)d_in[1];
    const float* anova  = (const float*)d_in[2];
    const float* w1     = (const float*)d_in[3];
    const float* b1     = (const float*)d_in[4];
    const float* w2     = (const float*)d_in[5];
    const float* b2     = (const float*)d_in[6];
    const float* w3     = (const float*)d_in[7];
    const float* b3     = (const float*)d_in[8];
    const int* actions  = (const int*)d_in[9];
    const int* adj      = (const int*)d_in[10];
    float* out = (float*)d_out;

    char* ws = (char*)d_ws;
    float*     mean   = (float*)    (ws + 0);            // 800 f32
    float*     rstd   = (float*)    (ws + 4096);         // 800 f32
    _Float16*  Abf    = (_Float16*) (ws + 32768);        // 2048*800 fp16
    _Float16*  WbT    = (_Float16*) (ws + 3311616);      // 3200*800 fp16
    _Float16*  W2dT   = (_Float16*) (ws + 8433664);      // 384*3200 fp16
    _Float16*  emb    = (_Float16*) (ws + 10893312);     // 2048*3200 fp16
    float*     Hp     = (float*)    (ws + 24002560);     // KSPLIT*2048*384 f32 (end ~39.7 MB)

    // K1: stats (25) | ehh_w transpose (2500) | W2dT build incl. self-scatter (445)
    prep1_kernel<<<2970, 256, 0, stream>>>(states, ehh_w, adj, anova, w1,
                                           mean, rstd, WbT, W2dT);
    // K2: normalize -> Abf (fp16), vectorized 8/thread
    norm_kernel<<<800, 256, 0, stream>>>(states, mean, rstd, Abf);
    // K3: emb = leaky(A @ WbT^T)   M=2048 N=3200 K=800
    gemm_bt<true><<<dim3(16, 25, 1), 256, 0, stream>>>(Abf, WbT, emb, nullptr, KDIM, EHH, KDIM, 0);
    // K4: Hp = emb @ W2dT^T (split-K x5)   M=2048 N=384 K=3200
    gemm_bt<false><<<dim3(16, 3, KSPLIT), 256, 0, stream>>>(emb, W2dT, nullptr, Hp, EHH, NPAD,
                                                            EHH / KSPLIT, BATCH * NPAD);
    // K5: tail
    tail_kernel<<<(BATCH * NAG) / 256, 256, 0, stream>>>(Hp, b1, w2, b2, w3, b3, actions, out);
}